// Round 12
// baseline (933.236 us; speedup 1.0000x reference)
//
#include <hip/hip_runtime.h>
#include <hip/hip_bf16.h>
#include <math.h>

using bf16 = __hip_bfloat16;
typedef __attribute__((ext_vector_type(8))) short short8;
typedef __attribute__((ext_vector_type(4))) float f32x4;

__device__ __forceinline__ float b2f(bf16 v){ return __bfloat162float(v); }
__device__ __forceinline__ bf16 f2b(float v){ return __float2bfloat16(v); }
__device__ __forceinline__ float bs2f(short s){
  union{unsigned u; float f;} x; x.u = ((unsigned)(unsigned short)s)<<16; return x.f;
}
__device__ __forceinline__ float lo16(unsigned u){ union{unsigned x; float f;} v; v.x = u<<16;          return v.f; }
__device__ __forceinline__ float hi16(unsigned u){ union{unsigned x; float f;} v; v.x = u & 0xffff0000u; return v.f; }
__device__ __forceinline__ unsigned cvt_pk_bf16(float lo, float hi){
  unsigned r; asm("v_cvt_pk_bf16_f32 %0, %1, %2" : "=v"(r) : "v"(lo), "v"(hi)); return r;
}
__device__ __forceinline__ float hw_exp2(float x){ float r; asm("v_exp_f32 %0, %1" : "=v"(r) : "v"(x)); return r; }
__device__ __forceinline__ float hw_rcp(float x){ float r; asm("v_rcp_f32 %0, %1" : "=v"(r) : "v"(x)); return r; }
__device__ __forceinline__ float fast_sigmoid(float v){ return hw_rcp(1.f + hw_exp2(v * -1.44269504f)); }
__device__ __forceinline__ float fast_tanh(float v){ return 1.f - 2.f*hw_rcp(1.f + hw_exp2(v * 2.88539008f)); }

template<int A> __device__ __forceinline__ float act_fn(float v){
  if constexpr (A==1) return fmaxf(v, 0.f);
  else if constexpr (A==2) return v > 0.f ? v : 0.2f*v;
  else if constexpr (A==3) return fast_sigmoid(v);
  else if constexpr (A==4) return fast_tanh(v);
  else return v;
}

// code: 0 = plain slab16, 1..4 = warp-virtual wrapped layer (code-1), 5 = rg*net product
struct Srcs9 { const bf16* p[9]; int code[9]; };

// ---------------------------------------------------------------------------
// Implicit-GEMM conv via mfma_f32_16x16x32_bf16, slab16 in/out.
// r10/11 schedule (single-buffer LDS + XCD swizzle) with VALU-slimmed math.
// code=5 staging computes rg*net on the fly (correctness proven in r5).
// A-frag: m=lane&15, k=(lane>>4)*8+j ; B-frag: n=lane&15 ; D: row=(lane>>4)*4+reg.
// LDS: [HH][24] bf16 (48B/px = 3x16B aligned; 56B's 8B-align was 3.5x slow, r8).
// ---------------------------------------------------------------------------
template<int KK, int ACT, int NT>
__global__ __launch_bounds__(256) void conv_mfma(
    Srcs9 S, int Gin, const bf16* __restrict__ flows, const bf16* __restrict__ rgp,
    const bf16* __restrict__ Bw, const float* __restrict__ bias,
    bf16* __restrict__ outS, size_t slabS, float* __restrict__ outF, int Cout,
    int H, int W)
{
  constexpr int TS=16, HALO=TS+KK-1, PAD=KK/2, NPAIR=(KK*KK+1)/2, HH=HALO*HALO;
  constexpr int CP=24, CPB=48;
  constexpr int NMT = (NT==1)?4:((NT==2)?8:16);
  __shared__ __align__(16) bf16 As[HH*CP];      // single buffer
  const int tid=threadIdx.x, lane=tid&63, wv=tid>>6;
  const int ln=lane&15, gq=lane>>4;
  const int tilesx=W/TS;
  // XCD swizzle: grid.x (1024, %8==0) -> contiguous strip per XCD
  const int nwg = gridDim.x, cpx = nwg >> 3;
  const int bidx = (blockIdx.x & 7)*cpx + (blockIdx.x >> 3);
  const int tx0 = (bidx % tilesx)*TS, ty0 = (bidx / tilesx)*TS;
  const int b=blockIdx.z; const int HW=H*W;
  int ntile, mt0;
  if constexpr (NT==1){ ntile=0;    mt0=wv*4; }
  else if constexpr (NT==2){ ntile=wv&1; mt0=(wv>>1)*8; }
  else { ntile=wv; mt0=0; }

  f32x4 acc[NMT];
  #pragma unroll
  for (int t=0;t<NMT;++t) acc[t]=(f32x4){0.f,0.f,0.f,0.f};

  const short8 Z8 = {0,0,0,0,0,0,0,0};
  const int px0=tid, px1=tid+256;
  const int hy0=px0/HALO, hx0=px0-hy0*HALO;
  const int hy1=px1/HALO, hx1=px1-hy1*HALO;
  const bool act1 = (px1<HH);
  const int gy0=ty0+hy0-PAD, gx0=tx0+hx0-PAD;
  const int gy1=ty0+hy1-PAD, gx1=tx0+hx1-PAD;
  const bool in0 = (gy0>=0&&gy0<H&&gx0>=0&&gx0<W);
  const bool in1 = act1 && (gy1>=0&&gy1<H&&gx1>=0&&gx1<W);
  const size_t po0 = ((size_t)b*HW + (size_t)(in0?gy0:0)*W + (in0?gx0:0))*16;
  const size_t po1 = ((size_t)b*HW + (size_t)(in1?gy1:0)*W + (in1?gx1:0))*16;

  auto gather = [&](int g, bool inb, size_t po, int gy, int gx, short8& A0, short8& A1){
    const int code = S.code[g];
    const bf16* sp = S.p[g];
    if (code == 0) {
      if (inb) {
        const bf16* qp = sp + po;
        A0 = *(const short8*)qp; A1 = *(const short8*)(qp+8);
      } else { A0 = Z8; A1 = Z8; }
    } else if (code == 5) {
      if (inb) {
        unsigned nu[8], ru[8], od[8];
        *(uint4*)nu     = *(const uint4*)(sp + po);  *(uint4*)(nu+4) = *(const uint4*)(sp + po + 8);
        *(uint4*)ru     = *(const uint4*)(rgp + po); *(uint4*)(ru+4) = *(const uint4*)(rgp + po + 8);
        #pragma unroll
        for (int j=0;j<8;++j)
          od[j] = cvt_pk_bf16(lo16(nu[j])*lo16(ru[j]), hi16(nu[j])*hi16(ru[j]));
        A0 = *(const short8*)od; A1 = *(const short8*)(od+4);
      } else { A0 = Z8; A1 = Z8; }
    } else {
      if (inb) {
        const int l = code-1;
        const unsigned fp_ = *(const unsigned*)(flows + po + 2*l);
        const float fx = lo16(fp_), fy = hi16(fp_);
        const float vgx = (float)gx - fx, vgy = (float)gy - fy;
        const float gxn = 2.f*vgx/(float)(W-1) - 1.f;
        const float gyn = 2.f*vgy/(float)(H-1) - 1.f;
        const float ix = ((gxn+1.f)*(float)W - 1.f)*0.5f;
        const float iy = ((gyn+1.f)*(float)H - 1.f)*0.5f;
        const float x0f = floorf(ix), y0f = floorf(iy);
        const float wx1 = ix-x0f, wy1 = iy-y0f, wx0 = 1.f-wx1, wy0 = 1.f-wy1;
        const int x0=(int)x0f, y0=(int)y0f, x1=x0+1, y1=y0+1;
        const bool vx0=(x0>=0)&(x0<W), vx1=(x1>=0)&(x1<W);
        const bool vy0=(y0>=0)&(y0<H), vy1=(y1>=0)&(y1<H);
        const int xc0=min(max(x0,0),W-1), xc1=min(max(x1,0),W-1);
        const int yc0=min(max(y0,0),H-1), yc1=min(max(y1,0),H-1);
        const float w00=wx0*wy0*((vx0&&vy0)?1.f:0.f);
        const float w10=wx1*wy0*((vx1&&vy0)?1.f:0.f);
        const float w01=wx0*wy1*((vx0&&vy1)?1.f:0.f);
        const float w11=wx1*wy1*((vx1&&vy1)?1.f:0.f);
        const bf16* nb = sp + (size_t)b*HW*16;
        const bf16* p00 = nb + ((size_t)yc0*W+xc0)*16;
        const bf16* p10 = nb + ((size_t)yc0*W+xc1)*16;
        const bf16* p01 = nb + ((size_t)yc1*W+xc0)*16;
        const bf16* p11 = nb + ((size_t)yc1*W+xc1)*16;
        unsigned t00[8], t10[8], t01[8], t11[8], od[8];
        *(uint4*)t00     = *(const uint4*)p00; *(uint4*)(t00+4) = *(const uint4*)(p00+8);
        *(uint4*)t10     = *(const uint4*)p10; *(uint4*)(t10+4) = *(const uint4*)(p10+8);
        *(uint4*)t01     = *(const uint4*)p01; *(uint4*)(t01+4) = *(const uint4*)(p01+8);
        *(uint4*)t11     = *(const uint4*)p11; *(uint4*)(t11+4) = *(const uint4*)(p11+8);
        #pragma unroll
        for (int j=0;j<8;++j){
          const float lo = w00*lo16(t00[j]) + w10*lo16(t10[j]) + w01*lo16(t01[j]) + w11*lo16(t11[j]);
          const float hi = w00*hi16(t00[j]) + w10*hi16(t10[j]) + w01*hi16(t01[j]) + w11*hi16(t11[j]);
          od[j] = cvt_pk_bf16(lo, hi);
        }
        A0 = *(const short8*)od; A1 = *(const short8*)(od+4);
      } else { A0 = Z8; A1 = Z8; }
    }
  };

  // hoisted MFMA addressing: t-term folds into ds_read offset immediates.
  auto mfma_g = [&](int g){
    const bf16* bw = Bw + ((size_t)g*NPAIR*NT + ntile)*512;
    const char* bufm = (const char*)As + (size_t)mt0*(HALO*CPB);
    #pragma unroll
    for (int p=0;p<NPAIR;++p){
      const short8 bfrag = *(const short8*)(bw + (size_t)p*(NT*512) + lane*8);
      int off = 2*p + (gq>>1);
      if (off >= KK*KK) off = 0;               // pad tap: B is zero there
      const int dy = off/KK, dx = off - (off/KK)*KK;
      const int ce = (dy*HALO + ln + dx)*CPB + ((gq&1)<<4);
      #pragma unroll
      for (int t=0;t<NMT;++t){
        const short8 af = *(const short8*)(bufm + (size_t)t*(HALO*CPB) + ce);
        acc[t] = __builtin_amdgcn_mfma_f32_16x16x32_bf16(af, bfrag, acc[t], 0, 0, 0);
      }
    }
  };

  for (int g=0; g<Gin; ++g) {
    short8 a0, a1, c0v, c1v;
    gather(g, in0, po0, gy0, gx0, a0, a1);          // loads issue here...
    if (act1) gather(g, in1, po1, gy1, gx1, c0v, c1v);
    if (g > 0) { mfma_g(g-1); __syncthreads(); }    // ...and hide under g-1's MFMAs
    *(short8*)(As + (size_t)px0*CP)     = a0;
    *(short8*)(As + (size_t)px0*CP + 8) = a1;
    if (act1){
      *(short8*)(As + (size_t)px1*CP)     = c0v;
      *(short8*)(As + (size_t)px1*CP + 8) = c1v;
    }
    __syncthreads();
  }
  mfma_g(Gin-1);

  // ---- epilogue ----
  const int co = ntile*16 + ln;
  const float bv = bias[co];
  if (outS) {
    #pragma unroll
    for (int t=0;t<NMT;++t){
      const int y = ty0 + mt0 + t;
      bf16* op = outS + (size_t)ntile*slabS + ((size_t)b*HW + (size_t)y*W + tx0 + gq*4)*16 + ln;
      const float f0 = act_fn<ACT>(acc[t][0] + bv);
      const float f1 = act_fn<ACT>(acc[t][1] + bv);
      const float f2 = act_fn<ACT>(acc[t][2] + bv);
      const float f3 = act_fn<ACT>(acc[t][3] + bv);
      const unsigned p01 = cvt_pk_bf16(f0, f1), p23 = cvt_pk_bf16(f2, f3);
      unsigned short* os = (unsigned short*)op;
      os[0]  = (unsigned short)p01; os[16] = (unsigned short)(p01>>16);
      os[32] = (unsigned short)p23; os[48] = (unsigned short)(p23>>16);
    }
  } else {
    if (co < Cout) {
      #pragma unroll
      for (int t=0;t<NMT;++t){
        const int y = ty0 + mt0 + t;
        float4 f;
        f.x = act_fn<ACT>(acc[t][0]+bv); f.y = act_fn<ACT>(acc[t][1]+bv);
        f.z = act_fn<ACT>(acc[t][2]+bv); f.w = act_fn<ACT>(acc[t][3]+bv);
        *(float4*)(outF + ((size_t)b*Cout + co)*HW + (size_t)y*W + tx0 + gq*4) = f;
      }
    }
  }
}

// ---- weight prepass descs ----
struct PrepDesc {
  const float *W1, *W2, *b1, *b2;
  int coSplit, NPAIR, NTp, Cout, CinO, T;
  int lo0, hi0, d2, lo2, hi2;
  int base[9];
  int total;
};
struct PrepAll { PrepDesc d[10]; int n; };

__device__ __forceinline__ void prep_body(const PrepAll& P, bf16* Bw, float* bOut,
                                          int grand, int i){
  if (i < P.n*64) {
    const int c=i>>6, t=i&63; const PrepDesc& D=P.d[c];
    float bv=0.f;
    if (t < D.Cout) bv = (!D.b2 || t < D.coSplit) ? D.b1[t] : D.b2[t-D.coSplit];
    bOut[c*64+t]=bv;
  }
  if (i >= grand) return;
  int c=0, off0=0;
  while (i >= off0 + P.d[c].total) { off0 += P.d[c].total; ++c; }
  const PrepDesc& D = P.d[c];
  const int j = i - off0;
  const int jj=j&7, l=(j>>3)&63, ln2=l&15, gq2=l>>4;
  int r=j>>9; const int nt=r%D.NTp; r/=D.NTp; const int p=r%D.NPAIR; const int g=r/D.NPAIR;
  const int k=gq2*8+jj, off=2*p+(k>>4), ci=k&15, co=nt*16+ln2;
  float w=0.f;
  if (off<D.T && co<D.Cout) {
    const int lo = (g==0)?D.lo0:0, hi=(g==0)?D.hi0:16;
    if (!D.W2 || co < D.coSplit) {
      if (ci>=lo && ci<hi) w = D.W1[((size_t)co*D.CinO + D.base[g]+ci)*D.T + off];
    } else {
      if (ci>=D.lo2 && ci<D.hi2) w = D.W2[((size_t)(co-D.coSplit)*D.CinO + D.base[g]+ci+D.d2)*D.T + off];
    }
  }
  Bw[i] = f2b(w);
}

__global__ void prep_w(PrepAll P, bf16* __restrict__ Bw, float* __restrict__ bOut, int grand){
  prep_body(P, Bw, bOut, grand, blockIdx.x*256 + threadIdx.x);
}

// ---- fused: weight prepass (y==B) + input packing (y<B) in ONE launch ----
__global__ void prep_pack(PrepAll P, bf16* __restrict__ Bw, float* __restrict__ bOut, int grand,
                          const float* __restrict__ corr, const float* __restrict__ noise,
                          const float* __restrict__ inp, const float* __restrict__ net,
                          bf16* __restrict__ cnoise, bf16* __restrict__ inpT,
                          bf16* __restrict__ netT, int HW)
{
  const int b = blockIdx.y;
  if (b >= 4) { prep_body(P, Bw, bOut, grand, blockIdx.x*256 + threadIdx.x); return; }
  const int px = blockIdx.x*256+threadIdx.x;
  if (px>=HW) return;
  const size_t base = ((size_t)b*HW+px)*16;
  __align__(16) bf16 t[16];
  #pragma unroll
  for (int c=0;c<16;++c) t[c]=f2b(0.f);
  #pragma unroll
  for (int c=0;c<3;++c){
    t[c]   = f2b(corr [((size_t)b*3+c)*HW+px]);
    t[3+c] = f2b(noise[((size_t)b*3+c)*HW+px]);
  }
  *(short8*)(cnoise+base) = *(const short8*)t; *(short8*)(cnoise+base+8) = *(const short8*)(t+8);
  #pragma unroll
  for (int c=0;c<16;++c) t[c]=f2b(inp[((size_t)b*16+c)*HW+px]);
  *(short8*)(inpT+base) = *(const short8*)t; *(short8*)(inpT+base+8) = *(const short8*)(t+8);
  #pragma unroll
  for (int c=0;c<16;++c) t[c]=f2b(net[((size_t)b*16+c)*HW+px]);
  *(short8*)(netT+base) = *(const short8*)t; *(short8*)(netT+base+8) = *(const short8*)(t+8);
}

__global__ void noise_tail(const float* __restrict__ noise, bf16* __restrict__ mslab3, int HW){
  const int px = blockIdx.x*256+threadIdx.x; const int b=blockIdx.y;
  if (px>=HW) return;
  bf16* d = mslab3 + ((size_t)b*HW+px)*16;
  #pragma unroll
  for (int c=0;c<3;++c) d[13+c] = f2b(noise[((size_t)b*3+c)*HW+px]);
}

// h1 = (1-zg)*net + zg*q  (netT slab16 source)
__global__ void h1_k(const bf16* __restrict__ zg, const bf16* __restrict__ q,
                     const bf16* __restrict__ netT, bf16* __restrict__ hT, int HW){
  const int px = blockIdx.x*256+threadIdx.x; const int b=blockIdx.y;
  if (px>=HW) return;
  const size_t base = ((size_t)b*HW+px)*16;
  const short8 z0=*(const short8*)(zg+base), z1=*(const short8*)(zg+base+8);
  const short8 q0=*(const short8*)(q+base),  q1=*(const short8*)(q+base+8);
  const short8 n0=*(const short8*)(netT+base), n1=*(const short8*)(netT+base+8);
  __align__(16) bf16 t[16];
  #pragma unroll
  for (int c=0;c<8;++c){
    const float za=bs2f(z0[c]), zb=bs2f(z1[c]);
    t[c]   = f2b((1.f-za)*bs2f(n0[c]) + za*bs2f(q0[c]));
    t[8+c] = f2b((1.f-zb)*bs2f(n1[c]) + zb*bs2f(q1[c]));
  }
  *(short8*)(hT+base) = *(const short8*)t; *(short8*)(hT+base+8) = *(const short8*)(t+8);
}

__global__ __launch_bounds__(256) void castats_p1(const bf16* __restrict__ hT,
                                                  float* __restrict__ part, int HW){
  const int blk=blockIdx.x, b=blockIdx.y;
  const int per = HW>>5;
  const bf16* base = hT + ((size_t)b*HW + (size_t)blk*per)*16;
  float s[16], m[16];
  #pragma unroll
  for (int c=0;c<16;++c){ s[c]=0.f; m[c]=-3.4e38f; }
  for (int i=threadIdx.x;i<per;i+=256){
    const short8 a=*(const short8*)(base+(size_t)i*16);
    const short8 bb=*(const short8*)(base+(size_t)i*16+8);
    #pragma unroll
    for (int c=0;c<8;++c){
      const float v=bs2f(a[c]);  s[c]+=v;   m[c]=fmaxf(m[c],v);
      const float w=bs2f(bb[c]); s[8+c]+=w; m[8+c]=fmaxf(m[8+c],w);
    }
  }
  #pragma unroll
  for (int o=32;o>=1;o>>=1){
    #pragma unroll
    for (int c=0;c<16;++c){ s[c]+=__shfl_down(s[c],o); m[c]=fmaxf(m[c],__shfl_down(m[c],o)); }
  }
  __shared__ float ls[4][16], lm[4][16];
  const int w4=threadIdx.x>>6;
  if ((threadIdx.x&63)==0){
    #pragma unroll
    for (int c=0;c<16;++c){ ls[w4][c]=s[c]; lm[w4][c]=m[c]; }
  }
  __syncthreads();
  if (threadIdx.x<16){
    const int c=threadIdx.x;
    part[((size_t)(b*32+blk))*32 + c]      = ls[0][c]+ls[1][c]+ls[2][c]+ls[3][c];
    part[((size_t)(b*32+blk))*32 + 16 + c] = fmaxf(fmaxf(lm[0][c],lm[1][c]),fmaxf(lm[2][c],lm[3][c]));
  }
}

// final CA reduce + channel-attention scale in one launch
__global__ void castats_fin(const float* __restrict__ part, const float* __restrict__ w1,
                            const float* __restrict__ w2, float* __restrict__ scale, int HW){
  const int t = threadIdx.x; if (t>=64) return;
  const int b=t>>4, c=t&15;
  float s=0.f, m=-3.4e38f;
  for (int k=0;k<32;++k){
    s += part[((size_t)(b*32+k))*32 + c];
    m  = fmaxf(m, part[((size_t)(b*32+k))*32 + 16 + c]);
  }
  float pa = w1[c]*(s/(float)HW), pm = w1[c]*m;
  #pragma unroll
  for (int o=8;o>=1;o>>=1){ pa += __shfl_xor(pa,o,16); pm += __shfl_xor(pm,o,16); }
  const float y = w2[c]*fmaxf(pa,0.f) + w2[c]*fmaxf(pm,0.f);
  scale[t] = fast_sigmoid(y);
}

__global__ void sastats_k(const bf16* __restrict__ hT, const float* __restrict__ scale,
                          bf16* __restrict__ sa2, int HW){
  const int px = blockIdx.x*256+threadIdx.x; const int b=blockIdx.y;
  if (px>=HW) return;
  const size_t base = ((size_t)b*HW+px)*16;
  const short8 a=*(const short8*)(hT+base), c8=*(const short8*)(hT+base+8);
  float s=0.f, m=-3.4e38f;
  #pragma unroll
  for (int c=0;c<8;++c){
    const float v=bs2f(a[c])*scale[b*16+c];    s+=v; m=fmaxf(m,v);
    const float w=bs2f(c8[c])*scale[b*16+8+c]; s+=w; m=fmaxf(m,w);
  }
  sa2[((size_t)b*2+0)*HW+px] = f2b(s*(1.f/16.f));
  sa2[((size_t)b*2+1)*HW+px] = f2b(m);
}

// spatial-attention 7x7 conv + sigmoid + final h scale, fused
__global__ __launch_bounds__(256) void hfinal2(bf16* __restrict__ hT, const float* __restrict__ scale,
    const bf16* __restrict__ sa2, const float* __restrict__ saw,
    float* __restrict__ outh, int H, int W){
  __shared__ float wl[98];
  if (threadIdx.x < 98) wl[threadIdx.x] = saw[threadIdx.x];
  __syncthreads();
  const int i = blockIdx.x*256 + threadIdx.x; const int b = blockIdx.y;
  const int HW = H*W;
  if (i >= HW) return;
  const int y = i / W, x = i - (i/W)*W;
  float s = 0.f;
  #pragma unroll
  for (int ch=0; ch<2; ++ch){
    const size_t base = ((size_t)b*2+ch)*HW;
    for (int ky=0;ky<7;++ky){
      const int yy=y+ky-3; if (yy<0||yy>=H) continue;
      for (int kx=0;kx<7;++kx){
        const int xx=x+kx-3; if (xx<0||xx>=W) continue;
        s += b2f(sa2[base+(size_t)yy*W+xx]) * wl[ch*49+ky*7+kx];
      }
    }
  }
  const float sa = fast_sigmoid(s);
  const size_t base = ((size_t)b*HW+i)*16;
  const short8 a=*(const short8*)(hT+base), c8=*(const short8*)(hT+base+8);
  __align__(16) bf16 t[16];
  #pragma unroll
  for (int c=0;c<8;++c){
    const float v=bs2f(a[c])*scale[b*16+c]*sa;
    const float w=bs2f(c8[c])*scale[b*16+8+c]*sa;
    t[c]=f2b(v); t[8+c]=f2b(w);
    outh[((size_t)b*16+c)*HW+i]=v; outh[((size_t)b*16+8+c)*HW+i]=w;
  }
  *(short8*)(hT+base)=*(const short8*)t; *(short8*)(hT+base+8)=*(const short8*)(t+8);
}

extern "C" void kernel_launch(void* const* d_in, const int* in_sizes, int n_in,
                              void* d_out, int out_size, void* d_ws, size_t ws_size,
                              hipStream_t stream)
{
  const float* net   = (const float*)d_in[0];
  const float* inp   = (const float*)d_in[1];
  const float* corr  = (const float*)d_in[2];
  const float* noise = (const float*)d_in[3];
  const float* wc1 = (const float*)d_in[4];  const float* bc1 = (const float*)d_in[5];
  const float* wc2 = (const float*)d_in[6];  const float* bc2 = (const float*)d_in[7];
  const float* wf1 = (const float*)d_in[8];  const float* bf1 = (const float*)d_in[9];
  const float* wf2 = (const float*)d_in[10]; const float* bf2 = (const float*)d_in[11];
  const float* we  = (const float*)d_in[12]; const float* be  = (const float*)d_in[13];
  const float* loc1_w = (const float*)d_in[14]; const float* loc1_b = (const float*)d_in[15];
  const float* loc2_w = (const float*)d_in[16]; const float* loc2_b = (const float*)d_in[17];
  const float* wz = (const float*)d_in[18]; const float* bz = (const float*)d_in[19];
  const float* wr = (const float*)d_in[20]; const float* br = (const float*)d_in[21];
  const float* wq = (const float*)d_in[22]; const float* bq = (const float*)d_in[23];
  const float* ca_w1 = (const float*)d_in[24]; const float* ca_w2 = (const float*)d_in[25];
  const float* sa_w  = (const float*)d_in[26];
  const float* fh1_w = (const float*)d_in[27]; const float* fh1_b = (const float*)d_in[28];
  const float* fh2_w = (const float*)d_in[29]; const float* fh2_b = (const float*)d_in[30];

  const int B = 4, H = 512, W = 512, HW = H*W;
  const size_t U  = 32ull<<20;              // one 16-ch slab [B][HW][16] bf16
  const size_t SS = (size_t)B*HW*16;        // slab stride (elements)
  char* ws = (char*)d_ws;

  // workspace units (256 MiB = 8): audited plan (r6/r10)
  bf16* cor1   = (bf16*)(ws + 0*U);
  bf16* flo1   = (bf16*)(ws + 2*U);
  bf16* motion = (bf16*)(ws + 0*U);
  bf16* fh1o   = (bf16*)(ws + 0*U);
  bf16* inpT   = (bf16*)(ws + 4*U);
  bf16* flo2   = (bf16*)(ws + 5*U);   // u5-6
  bf16* flows  = (bf16*)(ws + 5*U);   // u5 (after flo2 dead)
  bf16* qb     = (bf16*)(ws + 5*U);   // u5 (after flows dead)
  bf16* cnoise = (bf16*)(ws + 6*U);   // u6 (dead after merged conv)
  bf16* tbuf   = (bf16*)(ws + 6*U);   // u6 (after flo2 dead)
  bf16* hT     = (bf16*)(ws + 6*U);   // u6 (after tbuf dead)
  bf16* netT   = (bf16*)(ws + 7*U);
  float* part    = (float*)(ws + 4*U);
  float* scale   = (float*)(ws + 4*U + (64<<10));
  bf16*  sa2     = (bf16*)(ws + 4*U + (1<<20));
  bf16*  Bw_fh2  = (bf16*)(ws + 4*U + (16<<20));
  float* bias_fh2= (float*)(ws + 4*U + (17<<20));

  float* out_h  = (float*)d_out;
  float* out_df = out_h + (size_t)B*16*HW;
  bf16*  zgrg   = (bf16*)d_out;            // 2 slabs = exactly the h region
  bf16*  BwAll  = (bf16*)out_df;           // weights parked in df region
  float* biasAll= (float*)(BwAll + 190464);

  // Bw element offsets (cumsum)
  const size_t oMrg=0, oCor2=10240, oFlo2=20480, oMo=30720, oLoc1=71680,
               oLoc2=111616, oZgrg=118272, oQ=164352, oFh1=179712;
  const int grand = 189952;

  const dim3 pgrid((HW+255)/256, B);
  const dim3 cgrid((W/16)*(H/16), 1, B);

  auto mk = [](const float* W1, const float* W2, int coSplit, const float* b1, const float* b2,
               int G, int NP, int NTp, int Cout, int CinO, int T,
               int lo0, int hi0, int d2, int lo2, int hi2,
               int b0,int b1_,int b2_,int b3,int b4,int b5,int b6,int b7,int b8)->PrepDesc{
    PrepDesc d{};
    d.W1=W1; d.W2=W2; d.b1=b1; d.b2=b2; d.coSplit=coSplit;
    d.NPAIR=NP; d.NTp=NTp; d.Cout=Cout; d.CinO=CinO; d.T=T;
    d.lo0=lo0; d.hi0=hi0; d.d2=d2; d.lo2=lo2; d.hi2=hi2;
    const int bs[9]={b0,b1_,b2_,b3,b4,b5,b6,b7,b8};
    for (int g=0;g<9;++g) d.base[g]=bs[g];
    d.total = G*NP*NTp*512;
    return d;
  };

  // --- fused weight prepass + input packing (one launch) ---
  {
    PrepAll P{}; P.n = 9;
    P.d[0] = mk(wc1, wf1, 32, bc1, bf1, 1,5,4, 64,3,9,  0,3, -3,3,6, 0,0,0,0,0,0,0,0,0);   // cor1|flo1 merged
    P.d[1] = mk(wc2, nullptr,0, bc2,nullptr, 2,5,2, 32,32,9, 0,16, 0,0,16, 0,16,0,0,0,0,0,0,0);
    P.d[2] = mk(wf2, nullptr,0, bf2,nullptr, 2,5,2, 32,32,9, 0,16, 0,0,16, 0,16,0,0,0,0,0,0,0);
    P.d[3] = mk(we,  nullptr,0, be, nullptr, 4,5,4, 61,64,9, 0,16, 0,0,16, 0,16,32,48,0,0,0,0,0);
    P.d[4] = mk(loc1_w,nullptr,0, loc1_b,nullptr, 6,13,1, 16,96,25, 0,16, 0,0,16, 0,16,32,48,64,80,0,0,0);
    P.d[5] = mk(loc2_w,nullptr,0, loc2_b,nullptr, 1,13,1, 8,16,25,  0,16, 0,0,16, 0,0,0,0,0,0,0,0,0);
    P.d[6] = mk(wz, wr, 16, bz, br, 9,5,2, 32,144,9, 0,16, 0,0,16, 0,16,32,48,64,80,96,112,128);
    P.d[7] = mk(wq, nullptr,0, bq, nullptr, 6,5,1, 16,96,9, 0,16, 0,0,16, 0,16,32,48,64,80,0,0,0);
    P.d[8] = mk(fh1_w,nullptr,0, fh1_b,nullptr, 1,5,4, 64,16,9, 0,16, 0,0,16, 0,0,0,0,0,0,0,0,0);
    prep_pack<<<dim3((HW+255)/256, B+1),256,0,stream>>>(P, BwAll, biasAll, grand,
        corr, noise, inp, net, cnoise, inpT, netT, HW);
  }

  // --- motion encoder ---
  { Srcs9 S{}; S.p[0]=cnoise;   // merged cor1|flo1: co0-31 -> cor1 (u0-1), co32-63 -> flo1 (u2-3)
    conv_mfma<3,1,4><<<cgrid,256,0,stream>>>(S,1,nullptr,nullptr,BwAll+oMrg,biasAll+0*64,cor1,SS,nullptr,64,H,W); }
  { Srcs9 S{}; S.p[0]=cor1; S.p[1]=cor1+SS;
    conv_mfma<3,1,2><<<cgrid,256,0,stream>>>(S,2,nullptr,nullptr,BwAll+oCor2,biasAll+1*64,zgrg,SS,nullptr,32,H,W); }  // cor2 -> d_out scratch
  { Srcs9 S{}; S.p[0]=flo1; S.p[1]=flo1+SS;
    conv_mfma<3,1,2><<<cgrid,256,0,stream>>>(S,2,nullptr,nullptr,BwAll+oFlo2,biasAll+2*64,flo2,SS,nullptr,32,H,W); }
  { Srcs9 S{}; S.p[0]=zgrg; S.p[1]=zgrg+SS; S.p[2]=flo2; S.p[3]=flo2+SS;
    conv_mfma<3,1,4><<<cgrid,256,0,stream>>>(S,4,nullptr,nullptr,BwAll+oMo,biasAll+3*64,motion,SS,nullptr,61,H,W); }
  noise_tail<<<pgrid,256,0,stream>>>(noise, motion+3*SS, HW);

  // --- local flows ---
  { Srcs9 S{}; S.p[0]=inpT; S.p[1]=motion; S.p[2]=motion+SS; S.p[3]=motion+2*SS; S.p[4]=motion+3*SS; S.p[5]=netT;
    conv_mfma<5,2,1><<<cgrid,256,0,stream>>>(S,6,nullptr,nullptr,BwAll+oLoc1,biasAll+4*64,tbuf,SS,nullptr,16,H,W); }
  { Srcs9 S{}; S.p[0]=tbuf;
    conv_mfma<5,0,1><<<cgrid,256,0,stream>>>(S,1,nullptr,nullptr,BwAll+oLoc2,biasAll+5*64,flows,SS,nullptr,8,H,W); }

  // --- GRU: fused z|r conv, warp fused in staging ---
  { Srcs9 S{};
    S.p[0]=netT; S.code[0]=1; S.p[1]=netT; S.code[1]=2;
    S.p[2]=netT; S.code[2]=3; S.p[3]=netT; S.code[3]=4;
    S.p[4]=inpT; S.p[5]=motion; S.p[6]=motion+SS; S.p[7]=motion+2*SS; S.p[8]=motion+3*SS;
    conv_mfma<3,3,2><<<cgrid,256,0,stream>>>(S,9,flows,nullptr,BwAll+oZgrg,biasAll+6*64,zgrg,SS,nullptr,32,H,W); }
  { Srcs9 S{};  // q conv; group0 = rh computed on the fly (rg * net, code 5)
    S.p[0]=netT; S.code[0]=5;
    S.p[1]=inpT; S.p[2]=motion; S.p[3]=motion+SS; S.p[4]=motion+2*SS; S.p[5]=motion+3*SS;
    conv_mfma<3,4,1><<<cgrid,256,0,stream>>>(S,6,nullptr,zgrg+SS,BwAll+oQ,biasAll+7*64,qb,SS,nullptr,16,H,W); }
  h1_k<<<pgrid,256,0,stream>>>(zgrg, qb, netT, hT, HW);

  // --- fh2 weight prep (u4 free after q) ---
  { PrepAll P{}; P.n = 1;
    P.d[0] = mk(fh2_w,nullptr,0, fh2_b,nullptr, 4,5,1, 3,64,9, 0,16, 0,0,16, 0,16,32,48,0,0,0,0,0);
    prep_w<<<(10240+255)/256,256,0,stream>>>(P, Bw_fh2, bias_fh2, 10240); }

  // --- CBAM ---
  castats_p1<<<dim3(32,B),256,0,stream>>>(hT, part, HW);
  castats_fin<<<1,64,0,stream>>>(part, ca_w1, ca_w2, scale, HW);
  sastats_k<<<pgrid,256,0,stream>>>(hT, scale, sa2, HW);
  hfinal2<<<pgrid,256,0,stream>>>(hT, scale, sa2, sa_w, out_h, H, W);

  // --- FlowHead ---
  { Srcs9 S{}; S.p[0]=hT;
    conv_mfma<3,1,4><<<cgrid,256,0,stream>>>(S,1,nullptr,nullptr,BwAll+oFh1,biasAll+8*64,fh1o,SS,nullptr,64,H,W); }
  { Srcs9 S{}; S.p[0]=fh1o; S.p[1]=fh1o+SS; S.p[2]=fh1o+2*SS; S.p[3]=fh1o+3*SS;
    conv_mfma<3,0,1><<<cgrid,256,0,stream>>>(S,4,nullptr,nullptr,Bw_fh2,bias_fh2,nullptr,SS,out_df,3,H,W); }
}

// Round 13
// 871.891 us; speedup vs baseline: 1.0704x; 1.0704x over previous
//
#include <hip/hip_runtime.h>
#include <hip/hip_bf16.h>
#include <math.h>

using bf16 = __hip_bfloat16;
typedef __attribute__((ext_vector_type(8))) short short8;
typedef __attribute__((ext_vector_type(4))) float f32x4;

__device__ __forceinline__ float b2f(bf16 v){ return __bfloat162float(v); }
__device__ __forceinline__ bf16 f2b(float v){ return __float2bfloat16(v); }
__device__ __forceinline__ float bs2f(short s){
  union{unsigned u; float f;} x; x.u = ((unsigned)(unsigned short)s)<<16; return x.f;
}
__device__ __forceinline__ float lo16(unsigned u){ union{unsigned x; float f;} v; v.x = u<<16;          return v.f; }
__device__ __forceinline__ float hi16(unsigned u){ union{unsigned x; float f;} v; v.x = u & 0xffff0000u; return v.f; }
__device__ __forceinline__ unsigned cvt_pk_bf16(float lo, float hi){
  unsigned r; asm("v_cvt_pk_bf16_f32 %0, %1, %2" : "=v"(r) : "v"(lo), "v"(hi)); return r;
}
__device__ __forceinline__ float hw_exp2(float x){ float r; asm("v_exp_f32 %0, %1" : "=v"(r) : "v"(x)); return r; }
__device__ __forceinline__ float hw_rcp(float x){ float r; asm("v_rcp_f32 %0, %1" : "=v"(r) : "v"(x)); return r; }
__device__ __forceinline__ float fast_sigmoid(float v){ return hw_rcp(1.f + hw_exp2(v * -1.44269504f)); }
__device__ __forceinline__ float fast_tanh(float v){ return 1.f - 2.f*hw_rcp(1.f + hw_exp2(v * 2.88539008f)); }

template<int A> __device__ __forceinline__ float act_fn(float v){
  if constexpr (A==1) return fmaxf(v, 0.f);
  else if constexpr (A==2) return v > 0.f ? v : 0.2f*v;
  else if constexpr (A==3) return fast_sigmoid(v);
  else if constexpr (A==4) return fast_tanh(v);
  else return v;
}

// code: 0 = plain slab16, 1..4 = warp-virtual wrapped layer (code-1), 5 = rg*net (RG5 only)
struct Srcs9 { const bf16* p[9]; int code[9]; };

// ---------------------------------------------------------------------------
// Implicit-GEMM conv via mfma_f32_16x16x32_bf16, slab16 in/out.
// r11 schedule (single-buffer LDS + XCD swizzle + VALU-slim math).
// RG5 template bool gates the code-5 (rg*net) staging path so ONLY the q-conv
// instantiation pays its register pressure (r12 lesson: shared-lambda branch
// bloated ALL convs' VGPR 84->88, occupancy 31->22%).
// A-frag: m=lane&15, k=(lane>>4)*8+j ; B-frag: n=lane&15 ; D: row=(lane>>4)*4+reg.
// LDS: [HH][24] bf16 (48B/px = 3x16B aligned; 56B's 8B-align was 3.5x slow, r8).
// ---------------------------------------------------------------------------
template<int KK, int ACT, int NT, bool RG5=false>
__global__ __launch_bounds__(256) void conv_mfma(
    Srcs9 S, int Gin, const bf16* __restrict__ flows, const bf16* __restrict__ rgp,
    const bf16* __restrict__ Bw, const float* __restrict__ bias,
    bf16* __restrict__ outS, size_t slabS, float* __restrict__ outF, int Cout,
    int H, int W)
{
  constexpr int TS=16, HALO=TS+KK-1, PAD=KK/2, NPAIR=(KK*KK+1)/2, HH=HALO*HALO;
  constexpr int CP=24, CPB=48;
  constexpr int NMT = (NT==1)?4:((NT==2)?8:16);
  __shared__ __align__(16) bf16 As[HH*CP];      // single buffer
  const int tid=threadIdx.x, lane=tid&63, wv=tid>>6;
  const int ln=lane&15, gq=lane>>4;
  const int tilesx=W/TS;
  // XCD swizzle: grid.x (1024, %8==0) -> contiguous strip per XCD
  const int nwg = gridDim.x, cpx = nwg >> 3;
  const int bidx = (blockIdx.x & 7)*cpx + (blockIdx.x >> 3);
  const int tx0 = (bidx % tilesx)*TS, ty0 = (bidx / tilesx)*TS;
  const int b=blockIdx.z; const int HW=H*W;
  int ntile, mt0;
  if constexpr (NT==1){ ntile=0;    mt0=wv*4; }
  else if constexpr (NT==2){ ntile=wv&1; mt0=(wv>>1)*8; }
  else { ntile=wv; mt0=0; }

  f32x4 acc[NMT];
  #pragma unroll
  for (int t=0;t<NMT;++t) acc[t]=(f32x4){0.f,0.f,0.f,0.f};

  const short8 Z8 = {0,0,0,0,0,0,0,0};
  const int px0=tid, px1=tid+256;
  const int hy0=px0/HALO, hx0=px0-hy0*HALO;
  const int hy1=px1/HALO, hx1=px1-hy1*HALO;
  const bool act1 = (px1<HH);
  const int gy0=ty0+hy0-PAD, gx0=tx0+hx0-PAD;
  const int gy1=ty0+hy1-PAD, gx1=tx0+hx1-PAD;
  const bool in0 = (gy0>=0&&gy0<H&&gx0>=0&&gx0<W);
  const bool in1 = act1 && (gy1>=0&&gy1<H&&gx1>=0&&gx1<W);
  const size_t po0 = ((size_t)b*HW + (size_t)(in0?gy0:0)*W + (in0?gx0:0))*16;
  const size_t po1 = ((size_t)b*HW + (size_t)(in1?gy1:0)*W + (in1?gx1:0))*16;

  auto gather = [&](int g, bool inb, size_t po, int gy, int gx, short8& A0, short8& A1){
    const int code = S.code[g];
    const bf16* sp = S.p[g];
    if (code == 0) {
      if (inb) {
        const bf16* qp = sp + po;
        A0 = *(const short8*)qp; A1 = *(const short8*)(qp+8);
      } else { A0 = Z8; A1 = Z8; }
      return;
    }
    if constexpr (RG5) {
      if (code == 5) {
        if (inb) {
          unsigned nu[8], ru[8], od[8];
          *(uint4*)nu     = *(const uint4*)(sp + po);  *(uint4*)(nu+4) = *(const uint4*)(sp + po + 8);
          *(uint4*)ru     = *(const uint4*)(rgp + po); *(uint4*)(ru+4) = *(const uint4*)(rgp + po + 8);
          #pragma unroll
          for (int j=0;j<8;++j)
            od[j] = cvt_pk_bf16(lo16(nu[j])*lo16(ru[j]), hi16(nu[j])*hi16(ru[j]));
          A0 = *(const short8*)od; A1 = *(const short8*)(od+4);
        } else { A0 = Z8; A1 = Z8; }
        return;
      }
    }
    {
      if (inb) {
        const int l = code-1;
        const unsigned fp_ = *(const unsigned*)(flows + po + 2*l);
        const float fx = lo16(fp_), fy = hi16(fp_);
        const float vgx = (float)gx - fx, vgy = (float)gy - fy;
        const float gxn = 2.f*vgx/(float)(W-1) - 1.f;
        const float gyn = 2.f*vgy/(float)(H-1) - 1.f;
        const float ix = ((gxn+1.f)*(float)W - 1.f)*0.5f;
        const float iy = ((gyn+1.f)*(float)H - 1.f)*0.5f;
        const float x0f = floorf(ix), y0f = floorf(iy);
        const float wx1 = ix-x0f, wy1 = iy-y0f, wx0 = 1.f-wx1, wy0 = 1.f-wy1;
        const int x0=(int)x0f, y0=(int)y0f, x1=x0+1, y1=y0+1;
        const bool vx0=(x0>=0)&(x0<W), vx1=(x1>=0)&(x1<W);
        const bool vy0=(y0>=0)&(y0<H), vy1=(y1>=0)&(y1<H);
        const int xc0=min(max(x0,0),W-1), xc1=min(max(x1,0),W-1);
        const int yc0=min(max(y0,0),H-1), yc1=min(max(y1,0),H-1);
        const float w00=wx0*wy0*((vx0&&vy0)?1.f:0.f);
        const float w10=wx1*wy0*((vx1&&vy0)?1.f:0.f);
        const float w01=wx0*wy1*((vx0&&vy1)?1.f:0.f);
        const float w11=wx1*wy1*((vx1&&vy1)?1.f:0.f);
        const bf16* nb = sp + (size_t)b*HW*16;
        const bf16* p00 = nb + ((size_t)yc0*W+xc0)*16;
        const bf16* p10 = nb + ((size_t)yc0*W+xc1)*16;
        const bf16* p01 = nb + ((size_t)yc1*W+xc0)*16;
        const bf16* p11 = nb + ((size_t)yc1*W+xc1)*16;
        unsigned t00[8], t10[8], t01[8], t11[8], od[8];
        *(uint4*)t00     = *(const uint4*)p00; *(uint4*)(t00+4) = *(const uint4*)(p00+8);
        *(uint4*)t10     = *(const uint4*)p10; *(uint4*)(t10+4) = *(const uint4*)(p10+8);
        *(uint4*)t01     = *(const uint4*)p01; *(uint4*)(t01+4) = *(const uint4*)(p01+8);
        *(uint4*)t11     = *(const uint4*)p11; *(uint4*)(t11+4) = *(const uint4*)(p11+8);
        #pragma unroll
        for (int j=0;j<8;++j){
          const float lo = w00*lo16(t00[j]) + w10*lo16(t10[j]) + w01*lo16(t01[j]) + w11*lo16(t11[j]);
          const float hi = w00*hi16(t00[j]) + w10*hi16(t10[j]) + w01*hi16(t01[j]) + w11*hi16(t11[j]);
          od[j] = cvt_pk_bf16(lo, hi);
        }
        A0 = *(const short8*)od; A1 = *(const short8*)(od+4);
      } else { A0 = Z8; A1 = Z8; }
    }
  };

  // hoisted MFMA addressing: t-term folds into ds_read offset immediates.
  auto mfma_g = [&](int g){
    const bf16* bw = Bw + ((size_t)g*NPAIR*NT + ntile)*512;
    const char* bufm = (const char*)As + (size_t)mt0*(HALO*CPB);
    #pragma unroll
    for (int p=0;p<NPAIR;++p){
      const short8 bfrag = *(const short8*)(bw + (size_t)p*(NT*512) + lane*8);
      int off = 2*p + (gq>>1);
      if (off >= KK*KK) off = 0;               // pad tap: B is zero there
      const int dy = off/KK, dx = off - (off/KK)*KK;
      const int ce = (dy*HALO + ln + dx)*CPB + ((gq&1)<<4);
      #pragma unroll
      for (int t=0;t<NMT;++t){
        const short8 af = *(const short8*)(bufm + (size_t)t*(HALO*CPB) + ce);
        acc[t] = __builtin_amdgcn_mfma_f32_16x16x32_bf16(af, bfrag, acc[t], 0, 0, 0);
      }
    }
  };

  for (int g=0; g<Gin; ++g) {
    short8 a0, a1, c0v, c1v;
    gather(g, in0, po0, gy0, gx0, a0, a1);          // loads issue here...
    if (act1) gather(g, in1, po1, gy1, gx1, c0v, c1v);
    if (g > 0) { mfma_g(g-1); __syncthreads(); }    // ...and hide under g-1's MFMAs
    *(short8*)(As + (size_t)px0*CP)     = a0;
    *(short8*)(As + (size_t)px0*CP + 8) = a1;
    if (act1){
      *(short8*)(As + (size_t)px1*CP)     = c0v;
      *(short8*)(As + (size_t)px1*CP + 8) = c1v;
    }
    __syncthreads();
  }
  mfma_g(Gin-1);

  // ---- epilogue ----
  const int co = ntile*16 + ln;
  const float bv = bias[co];
  if (outS) {
    #pragma unroll
    for (int t=0;t<NMT;++t){
      const int y = ty0 + mt0 + t;
      bf16* op = outS + (size_t)ntile*slabS + ((size_t)b*HW + (size_t)y*W + tx0 + gq*4)*16 + ln;
      const float f0 = act_fn<ACT>(acc[t][0] + bv);
      const float f1 = act_fn<ACT>(acc[t][1] + bv);
      const float f2 = act_fn<ACT>(acc[t][2] + bv);
      const float f3 = act_fn<ACT>(acc[t][3] + bv);
      const unsigned p01 = cvt_pk_bf16(f0, f1), p23 = cvt_pk_bf16(f2, f3);
      unsigned short* os = (unsigned short*)op;
      os[0]  = (unsigned short)p01; os[16] = (unsigned short)(p01>>16);
      os[32] = (unsigned short)p23; os[48] = (unsigned short)(p23>>16);
    }
  } else {
    if (co < Cout) {
      #pragma unroll
      for (int t=0;t<NMT;++t){
        const int y = ty0 + mt0 + t;
        float4 f;
        f.x = act_fn<ACT>(acc[t][0]+bv); f.y = act_fn<ACT>(acc[t][1]+bv);
        f.z = act_fn<ACT>(acc[t][2]+bv); f.w = act_fn<ACT>(acc[t][3]+bv);
        *(float4*)(outF + ((size_t)b*Cout + co)*HW + (size_t)y*W + tx0 + gq*4) = f;
      }
    }
  }
}

// ---- weight prepass descs ----
struct PrepDesc {
  const float *W1, *W2, *b1, *b2;
  int coSplit, NPAIR, NTp, Cout, CinO, T;
  int lo0, hi0, d2, lo2, hi2;
  int base[9];
  int total;
};
struct PrepAll { PrepDesc d[10]; int n; };

__device__ __forceinline__ void prep_body(const PrepAll& P, bf16* Bw, float* bOut,
                                          int grand, int i){
  if (i < P.n*64) {
    const int c=i>>6, t=i&63; const PrepDesc& D=P.d[c];
    float bv=0.f;
    if (t < D.Cout) bv = (!D.b2 || t < D.coSplit) ? D.b1[t] : D.b2[t-D.coSplit];
    bOut[c*64+t]=bv;
  }
  if (i >= grand) return;
  int c=0, off0=0;
  while (i >= off0 + P.d[c].total) { off0 += P.d[c].total; ++c; }
  const PrepDesc& D = P.d[c];
  const int j = i - off0;
  const int jj=j&7, l=(j>>3)&63, ln2=l&15, gq2=l>>4;
  int r=j>>9; const int nt=r%D.NTp; r/=D.NTp; const int p=r%D.NPAIR; const int g=r/D.NPAIR;
  const int k=gq2*8+jj, off=2*p+(k>>4), ci=k&15, co=nt*16+ln2;
  float w=0.f;
  if (off<D.T && co<D.Cout) {
    const int lo = (g==0)?D.lo0:0, hi=(g==0)?D.hi0:16;
    if (!D.W2 || co < D.coSplit) {
      if (ci>=lo && ci<hi) w = D.W1[((size_t)co*D.CinO + D.base[g]+ci)*D.T + off];
    } else {
      if (ci>=D.lo2 && ci<D.hi2) w = D.W2[((size_t)(co-D.coSplit)*D.CinO + D.base[g]+ci+D.d2)*D.T + off];
    }
  }
  Bw[i] = f2b(w);
}

__global__ void prep_w(PrepAll P, bf16* __restrict__ Bw, float* __restrict__ bOut, int grand){
  prep_body(P, Bw, bOut, grand, blockIdx.x*256 + threadIdx.x);
}

// ---- fused: weight prepass (y==B) + input packing (y<B) in ONE launch ----
__global__ void prep_pack(PrepAll P, bf16* __restrict__ Bw, float* __restrict__ bOut, int grand,
                          const float* __restrict__ corr, const float* __restrict__ noise,
                          const float* __restrict__ inp, const float* __restrict__ net,
                          bf16* __restrict__ cnoise, bf16* __restrict__ inpT,
                          bf16* __restrict__ netT, int HW)
{
  const int b = blockIdx.y;
  if (b >= 4) { prep_body(P, Bw, bOut, grand, blockIdx.x*256 + threadIdx.x); return; }
  const int px = blockIdx.x*256+threadIdx.x;
  if (px>=HW) return;
  const size_t base = ((size_t)b*HW+px)*16;
  __align__(16) bf16 t[16];
  #pragma unroll
  for (int c=0;c<16;++c) t[c]=f2b(0.f);
  #pragma unroll
  for (int c=0;c<3;++c){
    t[c]   = f2b(corr [((size_t)b*3+c)*HW+px]);
    t[3+c] = f2b(noise[((size_t)b*3+c)*HW+px]);
  }
  *(short8*)(cnoise+base) = *(const short8*)t; *(short8*)(cnoise+base+8) = *(const short8*)(t+8);
  #pragma unroll
  for (int c=0;c<16;++c) t[c]=f2b(inp[((size_t)b*16+c)*HW+px]);
  *(short8*)(inpT+base) = *(const short8*)t; *(short8*)(inpT+base+8) = *(const short8*)(t+8);
  #pragma unroll
  for (int c=0;c<16;++c) t[c]=f2b(net[((size_t)b*16+c)*HW+px]);
  *(short8*)(netT+base) = *(const short8*)t; *(short8*)(netT+base+8) = *(const short8*)(t+8);
}

__global__ void noise_tail(const float* __restrict__ noise, bf16* __restrict__ mslab3, int HW){
  const int px = blockIdx.x*256+threadIdx.x; const int b=blockIdx.y;
  if (px>=HW) return;
  bf16* d = mslab3 + ((size_t)b*HW+px)*16;
  #pragma unroll
  for (int c=0;c<3;++c) d[13+c] = f2b(noise[((size_t)b*3+c)*HW+px]);
}

// rh = rg * net (slab16)
__global__ void rh_k(const bf16* __restrict__ rg, const bf16* __restrict__ netT,
                     bf16* __restrict__ rh, int HW){
  const int px = blockIdx.x*256+threadIdx.x; const int b=blockIdx.y;
  if (px>=HW) return;
  const size_t base = ((size_t)b*HW+px)*16;
  const short8 r0=*(const short8*)(rg+base),  r1=*(const short8*)(rg+base+8);
  const short8 n0=*(const short8*)(netT+base), n1=*(const short8*)(netT+base+8);
  __align__(16) bf16 t[16];
  #pragma unroll
  for (int c=0;c<8;++c){
    t[c]   = f2b(bs2f(r0[c])*bs2f(n0[c]));
    t[8+c] = f2b(bs2f(r1[c])*bs2f(n1[c]));
  }
  *(short8*)(rh+base) = *(const short8*)t; *(short8*)(rh+base+8) = *(const short8*)(t+8);
}

// h1 = (1-zg)*net + zg*q  (netT slab16 source)
__global__ void h1_k(const bf16* __restrict__ zg, const bf16* __restrict__ q,
                     const bf16* __restrict__ netT, bf16* __restrict__ hT, int HW){
  const int px = blockIdx.x*256+threadIdx.x; const int b=blockIdx.y;
  if (px>=HW) return;
  const size_t base = ((size_t)b*HW+px)*16;
  const short8 z0=*(const short8*)(zg+base), z1=*(const short8*)(zg+base+8);
  const short8 q0=*(const short8*)(q+base),  q1=*(const short8*)(q+base+8);
  const short8 n0=*(const short8*)(netT+base), n1=*(const short8*)(netT+base+8);
  __align__(16) bf16 t[16];
  #pragma unroll
  for (int c=0;c<8;++c){
    const float za=bs2f(z0[c]), zb=bs2f(z1[c]);
    t[c]   = f2b((1.f-za)*bs2f(n0[c]) + za*bs2f(q0[c]));
    t[8+c] = f2b((1.f-zb)*bs2f(n1[c]) + zb*bs2f(q1[c]));
  }
  *(short8*)(hT+base) = *(const short8*)t; *(short8*)(hT+base+8) = *(const short8*)(t+8);
}

__global__ __launch_bounds__(256) void castats_p1(const bf16* __restrict__ hT,
                                                  float* __restrict__ part, int HW){
  const int blk=blockIdx.x, b=blockIdx.y;
  const int per = HW>>5;
  const bf16* base = hT + ((size_t)b*HW + (size_t)blk*per)*16;
  float s[16], m[16];
  #pragma unroll
  for (int c=0;c<16;++c){ s[c]=0.f; m[c]=-3.4e38f; }
  for (int i=threadIdx.x;i<per;i+=256){
    const short8 a=*(const short8*)(base+(size_t)i*16);
    const short8 bb=*(const short8*)(base+(size_t)i*16+8);
    #pragma unroll
    for (int c=0;c<8;++c){
      const float v=bs2f(a[c]);  s[c]+=v;   m[c]=fmaxf(m[c],v);
      const float w=bs2f(bb[c]); s[8+c]+=w; m[8+c]=fmaxf(m[8+c],w);
    }
  }
  #pragma unroll
  for (int o=32;o>=1;o>>=1){
    #pragma unroll
    for (int c=0;c<16;++c){ s[c]+=__shfl_down(s[c],o); m[c]=fmaxf(m[c],__shfl_down(m[c],o)); }
  }
  __shared__ float ls[4][16], lm[4][16];
  const int w4=threadIdx.x>>6;
  if ((threadIdx.x&63)==0){
    #pragma unroll
    for (int c=0;c<16;++c){ ls[w4][c]=s[c]; lm[w4][c]=m[c]; }
  }
  __syncthreads();
  if (threadIdx.x<16){
    const int c=threadIdx.x;
    part[((size_t)(b*32+blk))*32 + c]      = ls[0][c]+ls[1][c]+ls[2][c]+ls[3][c];
    part[((size_t)(b*32+blk))*32 + 16 + c] = fmaxf(fmaxf(lm[0][c],lm[1][c]),fmaxf(lm[2][c],lm[3][c]));
  }
}

// final CA reduce + channel-attention scale in one launch
__global__ void castats_fin(const float* __restrict__ part, const float* __restrict__ w1,
                            const float* __restrict__ w2, float* __restrict__ scale, int HW){
  const int t = threadIdx.x; if (t>=64) return;
  const int b=t>>4, c=t&15;
  float s=0.f, m=-3.4e38f;
  for (int k=0;k<32;++k){
    s += part[((size_t)(b*32+k))*32 + c];
    m  = fmaxf(m, part[((size_t)(b*32+k))*32 + 16 + c]);
  }
  float pa = w1[c]*(s/(float)HW), pm = w1[c]*m;
  #pragma unroll
  for (int o=8;o>=1;o>>=1){ pa += __shfl_xor(pa,o,16); pm += __shfl_xor(pm,o,16); }
  const float y = w2[c]*fmaxf(pa,0.f) + w2[c]*fmaxf(pm,0.f);
  scale[t] = fast_sigmoid(y);
}

__global__ void sastats_k(const bf16* __restrict__ hT, const float* __restrict__ scale,
                          bf16* __restrict__ sa2, int HW){
  const int px = blockIdx.x*256+threadIdx.x; const int b=blockIdx.y;
  if (px>=HW) return;
  const size_t base = ((size_t)b*HW+px)*16;
  const short8 a=*(const short8*)(hT+base), c8=*(const short8*)(hT+base+8);
  float s=0.f, m=-3.4e38f;
  #pragma unroll
  for (int c=0;c<8;++c){
    const float v=bs2f(a[c])*scale[b*16+c];    s+=v; m=fmaxf(m,v);
    const float w=bs2f(c8[c])*scale[b*16+8+c]; s+=w; m=fmaxf(m,w);
  }
  sa2[((size_t)b*2+0)*HW+px] = f2b(s*(1.f/16.f));
  sa2[((size_t)b*2+1)*HW+px] = f2b(m);
}

// spatial-attention 7x7 conv + sigmoid + final h scale, fused
__global__ __launch_bounds__(256) void hfinal2(bf16* __restrict__ hT, const float* __restrict__ scale,
    const bf16* __restrict__ sa2, const float* __restrict__ saw,
    float* __restrict__ outh, int H, int W){
  __shared__ float wl[98];
  if (threadIdx.x < 98) wl[threadIdx.x] = saw[threadIdx.x];
  __syncthreads();
  const int i = blockIdx.x*256 + threadIdx.x; const int b = blockIdx.y;
  const int HW = H*W;
  if (i >= HW) return;
  const int y = i / W, x = i - (i/W)*W;
  float s = 0.f;
  #pragma unroll
  for (int ch=0; ch<2; ++ch){
    const size_t base = ((size_t)b*2+ch)*HW;
    for (int ky=0;ky<7;++ky){
      const int yy=y+ky-3; if (yy<0||yy>=H) continue;
      for (int kx=0;kx<7;++kx){
        const int xx=x+kx-3; if (xx<0||xx>=W) continue;
        s += b2f(sa2[base+(size_t)yy*W+xx]) * wl[ch*49+ky*7+kx];
      }
    }
  }
  const float sa = fast_sigmoid(s);
  const size_t base = ((size_t)b*HW+i)*16;
  const short8 a=*(const short8*)(hT+base), c8=*(const short8*)(hT+base+8);
  __align__(16) bf16 t[16];
  #pragma unroll
  for (int c=0;c<8;++c){
    const float v=bs2f(a[c])*scale[b*16+c]*sa;
    const float w=bs2f(c8[c])*scale[b*16+8+c]*sa;
    t[c]=f2b(v); t[8+c]=f2b(w);
    outh[((size_t)b*16+c)*HW+i]=v; outh[((size_t)b*16+8+c)*HW+i]=w;
  }
  *(short8*)(hT+base)=*(const short8*)t; *(short8*)(hT+base+8)=*(const short8*)(t+8);
}

extern "C" void kernel_launch(void* const* d_in, const int* in_sizes, int n_in,
                              void* d_out, int out_size, void* d_ws, size_t ws_size,
                              hipStream_t stream)
{
  const float* net   = (const float*)d_in[0];
  const float* inp   = (const float*)d_in[1];
  const float* corr  = (const float*)d_in[2];
  const float* noise = (const float*)d_in[3];
  const float* wc1 = (const float*)d_in[4];  const float* bc1 = (const float*)d_in[5];
  const float* wc2 = (const float*)d_in[6];  const float* bc2 = (const float*)d_in[7];
  const float* wf1 = (const float*)d_in[8];  const float* bf1 = (const float*)d_in[9];
  const float* wf2 = (const float*)d_in[10]; const float* bf2 = (const float*)d_in[11];
  const float* we  = (const float*)d_in[12]; const float* be  = (const float*)d_in[13];
  const float* loc1_w = (const float*)d_in[14]; const float* loc1_b = (const float*)d_in[15];
  const float* loc2_w = (const float*)d_in[16]; const float* loc2_b = (const float*)d_in[17];
  const float* wz = (const float*)d_in[18]; const float* bz = (const float*)d_in[19];
  const float* wr = (const float*)d_in[20]; const float* br = (const float*)d_in[21];
  const float* wq = (const float*)d_in[22]; const float* bq = (const float*)d_in[23];
  const float* ca_w1 = (const float*)d_in[24]; const float* ca_w2 = (const float*)d_in[25];
  const float* sa_w  = (const float*)d_in[26];
  const float* fh1_w = (const float*)d_in[27]; const float* fh1_b = (const float*)d_in[28];
  const float* fh2_w = (const float*)d_in[29]; const float* fh2_b = (const float*)d_in[30];

  const int B = 4, H = 512, W = 512, HW = H*W;
  const size_t U  = 32ull<<20;              // one 16-ch slab [B][HW][16] bf16
  const size_t SS = (size_t)B*HW*16;        // slab stride (elements)
  char* ws = (char*)d_ws;

  // workspace units (256 MiB = 8): audited plan (r6/r10)
  bf16* cor1   = (bf16*)(ws + 0*U);
  bf16* flo1   = (bf16*)(ws + 2*U);
  bf16* motion = (bf16*)(ws + 0*U);
  bf16* fh1o   = (bf16*)(ws + 0*U);
  bf16* inpT   = (bf16*)(ws + 4*U);
  bf16* flo2   = (bf16*)(ws + 5*U);   // u5-6
  bf16* flows  = (bf16*)(ws + 5*U);   // u5 (after flo2 dead)
  bf16* qb     = (bf16*)(ws + 5*U);   // u5 (after flows dead)
  bf16* cnoise = (bf16*)(ws + 6*U);   // u6 (dead after merged conv)
  bf16* tbuf   = (bf16*)(ws + 6*U);   // u6 (after flo2 dead)
  bf16* hT     = (bf16*)(ws + 6*U);   // u6 (after tbuf dead)
  bf16* netT   = (bf16*)(ws + 7*U);
  float* part    = (float*)(ws + 4*U);
  float* scale   = (float*)(ws + 4*U + (64<<10));
  bf16*  sa2     = (bf16*)(ws + 4*U + (1<<20));
  bf16*  Bw_fh2  = (bf16*)(ws + 4*U + (16<<20));
  float* bias_fh2= (float*)(ws + 4*U + (17<<20));

  float* out_h  = (float*)d_out;
  float* out_df = out_h + (size_t)B*16*HW;
  bf16*  zgrg   = (bf16*)d_out;            // 2 slabs = exactly the h region
  bf16*  BwAll  = (bf16*)out_df;           // weights parked in df region
  float* biasAll= (float*)(BwAll + 190464);

  // Bw element offsets (cumsum)
  const size_t oMrg=0, oCor2=10240, oFlo2=20480, oMo=30720, oLoc1=71680,
               oLoc2=111616, oZgrg=118272, oQ=164352, oFh1=179712;
  const int grand = 189952;

  const dim3 pgrid((HW+255)/256, B);
  const dim3 cgrid((W/16)*(H/16), 1, B);

  auto mk = [](const float* W1, const float* W2, int coSplit, const float* b1, const float* b2,
               int G, int NP, int NTp, int Cout, int CinO, int T,
               int lo0, int hi0, int d2, int lo2, int hi2,
               int b0,int b1_,int b2_,int b3,int b4,int b5,int b6,int b7,int b8)->PrepDesc{
    PrepDesc d{};
    d.W1=W1; d.W2=W2; d.b1=b1; d.b2=b2; d.coSplit=coSplit;
    d.NPAIR=NP; d.NTp=NTp; d.Cout=Cout; d.CinO=CinO; d.T=T;
    d.lo0=lo0; d.hi0=hi0; d.d2=d2; d.lo2=lo2; d.hi2=hi2;
    const int bs[9]={b0,b1_,b2_,b3,b4,b5,b6,b7,b8};
    for (int g=0;g<9;++g) d.base[g]=bs[g];
    d.total = G*NP*NTp*512;
    return d;
  };

  // --- fused weight prepass + input packing (one launch) ---
  {
    PrepAll P{}; P.n = 9;
    P.d[0] = mk(wc1, wf1, 32, bc1, bf1, 1,5,4, 64,3,9,  0,3, -3,3,6, 0,0,0,0,0,0,0,0,0);   // cor1|flo1 merged
    P.d[1] = mk(wc2, nullptr,0, bc2,nullptr, 2,5,2, 32,32,9, 0,16, 0,0,16, 0,16,0,0,0,0,0,0,0);
    P.d[2] = mk(wf2, nullptr,0, bf2,nullptr, 2,5,2, 32,32,9, 0,16, 0,0,16, 0,16,0,0,0,0,0,0,0);
    P.d[3] = mk(we,  nullptr,0, be, nullptr, 4,5,4, 61,64,9, 0,16, 0,0,16, 0,16,32,48,0,0,0,0,0);
    P.d[4] = mk(loc1_w,nullptr,0, loc1_b,nullptr, 6,13,1, 16,96,25, 0,16, 0,0,16, 0,16,32,48,64,80,0,0,0);
    P.d[5] = mk(loc2_w,nullptr,0, loc2_b,nullptr, 1,13,1, 8,16,25,  0,16, 0,0,16, 0,0,0,0,0,0,0,0,0);
    P.d[6] = mk(wz, wr, 16, bz, br, 9,5,2, 32,144,9, 0,16, 0,0,16, 0,16,32,48,64,80,96,112,128);
    P.d[7] = mk(wq, nullptr,0, bq, nullptr, 6,5,1, 16,96,9, 0,16, 0,0,16, 0,16,32,48,64,80,0,0,0);
    P.d[8] = mk(fh1_w,nullptr,0, fh1_b,nullptr, 1,5,4, 64,16,9, 0,16, 0,0,16, 0,0,0,0,0,0,0,0,0);
    prep_pack<<<dim3((HW+255)/256, B+1),256,0,stream>>>(P, BwAll, biasAll, grand,
        corr, noise, inp, net, cnoise, inpT, netT, HW);
  }

  // --- motion encoder ---
  { Srcs9 S{}; S.p[0]=cnoise;   // merged cor1|flo1: co0-31 -> cor1 (u0-1), co32-63 -> flo1 (u2-3)
    conv_mfma<3,1,4><<<cgrid,256,0,stream>>>(S,1,nullptr,nullptr,BwAll+oMrg,biasAll+0*64,cor1,SS,nullptr,64,H,W); }
  { Srcs9 S{}; S.p[0]=cor1; S.p[1]=cor1+SS;
    conv_mfma<3,1,2><<<cgrid,256,0,stream>>>(S,2,nullptr,nullptr,BwAll+oCor2,biasAll+1*64,zgrg,SS,nullptr,32,H,W); }  // cor2 -> d_out scratch
  { Srcs9 S{}; S.p[0]=flo1; S.p[1]=flo1+SS;
    conv_mfma<3,1,2><<<cgrid,256,0,stream>>>(S,2,nullptr,nullptr,BwAll+oFlo2,biasAll+2*64,flo2,SS,nullptr,32,H,W); }
  { Srcs9 S{}; S.p[0]=zgrg; S.p[1]=zgrg+SS; S.p[2]=flo2; S.p[3]=flo2+SS;
    conv_mfma<3,1,4><<<cgrid,256,0,stream>>>(S,4,nullptr,nullptr,BwAll+oMo,biasAll+3*64,motion,SS,nullptr,61,H,W); }
  noise_tail<<<pgrid,256,0,stream>>>(noise, motion+3*SS, HW);

  // --- local flows ---
  { Srcs9 S{}; S.p[0]=inpT; S.p[1]=motion; S.p[2]=motion+SS; S.p[3]=motion+2*SS; S.p[4]=motion+3*SS; S.p[5]=netT;
    conv_mfma<5,2,1><<<cgrid,256,0,stream>>>(S,6,nullptr,nullptr,BwAll+oLoc1,biasAll+4*64,tbuf,SS,nullptr,16,H,W); }
  { Srcs9 S{}; S.p[0]=tbuf;
    conv_mfma<5,0,1><<<cgrid,256,0,stream>>>(S,1,nullptr,nullptr,BwAll+oLoc2,biasAll+5*64,flows,SS,nullptr,8,H,W); }

  // --- GRU: fused z|r conv, warp fused in staging ---
  { Srcs9 S{};
    S.p[0]=netT; S.code[0]=1; S.p[1]=netT; S.code[1]=2;
    S.p[2]=netT; S.code[2]=3; S.p[3]=netT; S.code[3]=4;
    S.p[4]=inpT; S.p[5]=motion; S.p[6]=motion+SS; S.p[7]=motion+2*SS; S.p[8]=motion+3*SS;
    conv_mfma<3,3,2><<<cgrid,256,0,stream>>>(S,9,flows,nullptr,BwAll+oZgrg,biasAll+6*64,zgrg,SS,nullptr,32,H,W); }
  { Srcs9 S{};  // q conv; group0 = rh computed on the fly (rg * net, code 5; RG5 instantiation only)
    S.p[0]=netT; S.code[0]=5;
    S.p[1]=inpT; S.p[2]=motion; S.p[3]=motion+SS; S.p[4]=motion+2*SS; S.p[5]=motion+3*SS;
    conv_mfma<3,4,1,true><<<cgrid,256,0,stream>>>(S,6,nullptr,zgrg+SS,BwAll+oQ,biasAll+7*64,qb,SS,nullptr,16,H,W); }
  h1_k<<<pgrid,256,0,stream>>>(zgrg, qb, netT, hT, HW);

  // --- fh2 weight prep (u4 free after q) ---
  { PrepAll P{}; P.n = 1;
    P.d[0] = mk(fh2_w,nullptr,0, fh2_b,nullptr, 4,5,1, 3,64,9, 0,16, 0,0,16, 0,16,32,48,0,0,0,0,0);
    prep_w<<<(10240+255)/256,256,0,stream>>>(P, Bw_fh2, bias_fh2, 10240); }

  // --- CBAM ---
  castats_p1<<<dim3(32,B),256,0,stream>>>(hT, part, HW);
  castats_fin<<<1,64,0,stream>>>(part, ca_w1, ca_w2, scale, HW);
  sastats_k<<<pgrid,256,0,stream>>>(hT, scale, sa2, HW);
  hfinal2<<<pgrid,256,0,stream>>>(hT, scale, sa2, sa_w, out_h, H, W);

  // --- FlowHead ---
  { Srcs9 S{}; S.p[0]=hT;
    conv_mfma<3,1,4><<<cgrid,256,0,stream>>>(S,1,nullptr,nullptr,BwAll+oFh1,biasAll+8*64,fh1o,SS,nullptr,64,H,W); }
  { Srcs9 S{}; S.p[0]=fh1o; S.p[1]=fh1o+SS; S.p[2]=fh1o+2*SS; S.p[3]=fh1o+3*SS;
    conv_mfma<3,0,1><<<cgrid,256,0,stream>>>(S,4,nullptr,nullptr,Bw_fh2,bias_fh2,nullptr,SS,out_df,3,H,W); }
}